// Round 1
// baseline (111.384 us; speedup 1.0000x reference)
//
#include <hip/hip_runtime.h>

#define N 32768
#define P 8192
#define MX 8                          // x-values per wave (wave-uniform)
#define XG 2                          // x-groups per block
#define PH 2                          // pattern halves
#define THREADS (XG * PH * 64)        // 256
#define XPB (XG * MX)                 // 16 x per block
#define NBLK (N / XPB)                // 2048
#define PAIRS (P / 2)                 // 4096 pattern-pairs
#define PAIRS_PER_PH (PAIRS / PH)     // 2048
#define ITERS (PAIRS_PER_PH / 64)     // 32 (power of 2 — wrap prefetch)

// f = log2(e)/(2*sigma^2), sigma^2 = 1.44; per-x |x|^2 cancels in num/den.
#define RBF_F 0.50093577808645257f

// exp2 via main-pipe packed poly (for half the x's — trans-pipe load balancing):
// deg-5 Taylor of 2^f on [-0.5,0.5], |rel err| < 2.5e-6
#define EC1 0.69314718056f
#define EC2 0.24022650700f
#define EC3 0.05550410866f
#define EC4 0.00961812911f
#define EC5 0.00133335581f
#define EMAG 12582912.0f              // 1.5 * 2^23 — RNE round-to-int magic

typedef float v2f __attribute__((ext_vector_type(2)));
typedef int   v2i __attribute__((ext_vector_type(2)));

static __device__ __forceinline__ float fast_exp2(float x) {
#if __has_builtin(__builtin_amdgcn_exp2f)
    return __builtin_amdgcn_exp2f(x);
#else
    return exp2f(x);
#endif
}

// Pair-interleaved constants for pattern pair q = (2q, 2q+1):
//   c[2q]   = { c0(2q), c0(2q+1), c1(2q), c1(2q+1) }
//   c[2q+1] = { c2(2q), c2(2q+1), w(2q),  w(2q+1)  }
// pk ops consume the loaded register pairs directly — no repacking movs.
__global__ void prep_kernel(const float* __restrict__ pat,
                            const float* __restrict__ w2,
                            float4* __restrict__ c) {
    int q = blockIdx.x * blockDim.x + threadIdx.x;
    if (q < P / 2) {
        float p00 = pat[4 * q + 0], p01 = pat[4 * q + 1];
        float p10 = pat[4 * q + 2], p11 = pat[4 * q + 3];
        float4 a, b;
        a.x = 2.0f * RBF_F * p00;  a.y = 2.0f * RBF_F * p10;
        a.z = 2.0f * RBF_F * p01;  a.w = 2.0f * RBF_F * p11;
        b.x = -RBF_F * (p00 * p00 + p01 * p01);
        b.y = -RBF_F * (p10 * p10 + p11 * p11);
        b.z = w2[2 * q];           b.w = w2[2 * q + 1];
        c[2 * q]     = a;
        c[2 * q + 1] = b;
    }
}

__global__ __launch_bounds__(THREADS) void
rbf_kernel(const float* __restrict__ X,
           const float4* __restrict__ c,
           float* __restrict__ out) {
    const int t    = threadIdx.x;
    const int lane = t & 63;
    const int w    = __builtin_amdgcn_readfirstlane(t >> 6);  // 0..3
    const int xg   = w >> 1;
    const int ph   = w & 1;

    // 8 wave-uniform x-values, hoisted as persistent splat pairs
    const int xb = blockIdx.x * XPB + xg * MX;
    const float2* Xp = (const float2*)X;
    v2f xs0[MX], xs1[MX];
#pragma unroll
    for (int i = 0; i < MX; ++i) {
        float2 xv = Xp[xb + i];
        xs0[i] = (v2f){xv.x, xv.x};
        xs1[i] = (v2f){xv.y, xv.y};
    }

    v2f num2[MX], den2[MX];
#pragma unroll
    for (int i = 0; i < MX; ++i) {
        num2[i] = (v2f){0.f, 0.f};
        den2[i] = (v2f){0.f, 0.f};
    }

    // this wave's pattern-pair stream (L2-resident, coalesced 2 KB/wave/iter)
    const float4* __restrict__ C4 = c + (size_t)ph * (2 * PAIRS_PER_PH);

    float4 a = C4[2 * lane];
    float4 b = C4[2 * lane + 1];

    for (int j = 0; j < ITERS; ++j) {
        // branch-free wrapped prefetch of next iteration's pair
        const int qn = (((j + 1) & (ITERS - 1)) << 6) + lane;
        float4 an = C4[2 * qn];
        float4 bn = C4[2 * qn + 1];

#pragma unroll
        for (int i = 0; i < MX; i += 2) {
            // exp args for x_i and x_{i+1} at patterns (2q, 2q+1)
            v2f t0 = __builtin_elementwise_fma((v2f){a.x, a.y}, xs0[i],
                                               (v2f){b.x, b.y});
            t0 = __builtin_elementwise_fma((v2f){a.z, a.w}, xs1[i], t0);
            v2f t1 = __builtin_elementwise_fma((v2f){a.x, a.y}, xs0[i + 1],
                                               (v2f){b.x, b.y});
            t1 = __builtin_elementwise_fma((v2f){a.z, a.w}, xs1[i + 1], t1);

            // x_i: transcendental pipe
            v2f k0 = (v2f){fast_exp2(t0.x), fast_exp2(t0.y)};

            // x_{i+1}: main-pipe packed poly exp2
            v2f mm = t1 + (v2f){EMAG, EMAG};       // RNE int in mantissa bits
            v2f nn = mm - (v2f){EMAG, EMAG};       // n = rndne(t1)
            v2f ff = t1 - nn;                      // f in [-0.5, 0.5]
            v2f pp = __builtin_elementwise_fma(ff, (v2f){EC5, EC5},
                                               (v2f){EC4, EC4});
            pp = __builtin_elementwise_fma(ff, pp, (v2f){EC3, EC3});
            pp = __builtin_elementwise_fma(ff, pp, (v2f){EC2, EC2});
            pp = __builtin_elementwise_fma(ff, pp, (v2f){EC1, EC1});
            pp = __builtin_elementwise_fma(ff, pp, (v2f){1.0f, 1.0f});
            // k1 = pp * 2^n via exponent-bits add: (as_int(mm)<<23) wraps to n<<23
            v2i ki = (__builtin_bit_cast(v2i, mm) << 23) +
                     __builtin_bit_cast(v2i, pp);
            v2f k1 = __builtin_bit_cast(v2f, ki);

            den2[i]     += k0;
            num2[i]      = __builtin_elementwise_fma(k0, (v2f){b.z, b.w},
                                                     num2[i]);
            den2[i + 1] += k1;
            num2[i + 1]  = __builtin_elementwise_fma(k1, (v2f){b.z, b.w},
                                                     num2[i + 1]);
        }
        a = an;
        b = bn;
    }

    // fold pattern-pair halves, then 6-step butterfly across the wave
    float num[MX], den[MX];
#pragma unroll
    for (int i = 0; i < MX; ++i) {
        num[i] = num2[i].x + num2[i].y;
        den[i] = den2[i].x + den2[i].y;
    }
#pragma unroll
    for (int m = 1; m < 64; m <<= 1) {
#pragma unroll
        for (int i = 0; i < MX; ++i) {
            num[i] += __shfl_xor(num[i], m, 64);
            den[i] += __shfl_xor(den[i], m, 64);
        }
    }

    __shared__ float red[XG][PH][MX][2];
    if (lane == 0) {
#pragma unroll
        for (int i = 0; i < MX; ++i) {
            red[xg][ph][i][0] = num[i];
            red[xg][ph][i][1] = den[i];
        }
    }
    __syncthreads();

    if (t < XPB) {
        int g = t >> 3, xi = t & 7;
        float nn = red[g][0][xi][0] + red[g][1][xi][0];
        float dd = red[g][0][xi][1] + red[g][1][xi][1];
        out[blockIdx.x * XPB + t] = nn / dd;
    }
}

extern "C" void kernel_launch(void* const* d_in, const int* in_sizes, int n_in,
                              void* d_out, int out_size, void* d_ws, size_t ws_size,
                              hipStream_t stream) {
    const float* X   = (const float*)d_in[0];   // [32768, 2]
    const float* pat = (const float*)d_in[1];   // [8192, 2]
    const float* w2  = (const float*)d_in[2];   // [8192]
    float* out = (float*)d_out;                 // [32768]
    float4* c = (float4*)d_ws;                  // 8192 * 16 B = 128 KB

    prep_kernel<<<(P / 2 + 255) / 256, 256, 0, stream>>>(pat, w2, c);
    rbf_kernel<<<NBLK, THREADS, 0, stream>>>(X, c, out);
}

// Round 2
// 100.131 us; speedup vs baseline: 1.1124x; 1.1124x over previous
//
#include <hip/hip_runtime.h>

#define N 32768
#define P 8192
#define MX 4                          // x-values per wave (wave-uniform)
#define XG 2                          // x-groups per block
#define PH 2                          // pattern halves
#define THREADS (XG * PH * 64)        // 256
#define XPB (XG * MX)                 // 8 x per block
#define NBLK (N / XPB)                // 4096 (2x oversubscription: 16384 waves)
#define PAIRS (P / 2)                 // 4096 pattern-pairs
#define PAIRS_PER_PH (PAIRS / PH)     // 2048
#define ITERS (PAIRS_PER_PH / 64)     // 32 (power of 2 — wrap prefetch)

// f = log2(e)/(2*sigma^2), sigma^2 = 1.44; per-x |x|^2 cancels in num/den.
#define RBF_F 0.50093577808645257f

typedef float v2f __attribute__((ext_vector_type(2)));

static __device__ __forceinline__ float fast_exp2(float x) {
#if __has_builtin(__builtin_amdgcn_exp2f)
    return __builtin_amdgcn_exp2f(x);
#else
    return exp2f(x);
#endif
}

// Pair-interleaved constants for pattern pair q = (2q, 2q+1):
//   c[2q]   = { c0(2q), c0(2q+1), c1(2q), c1(2q+1) }
//   c[2q+1] = { c2(2q), c2(2q+1), w(2q),  w(2q+1)  }
// pk ops consume the loaded register pairs directly — no repacking movs.
__global__ void prep_kernel(const float* __restrict__ pat,
                            const float* __restrict__ w2,
                            float4* __restrict__ c) {
    int q = blockIdx.x * blockDim.x + threadIdx.x;
    if (q < P / 2) {
        float p00 = pat[4 * q + 0], p01 = pat[4 * q + 1];
        float p10 = pat[4 * q + 2], p11 = pat[4 * q + 3];
        float4 a, b;
        a.x = 2.0f * RBF_F * p00;  a.y = 2.0f * RBF_F * p10;
        a.z = 2.0f * RBF_F * p01;  a.w = 2.0f * RBF_F * p11;
        b.x = -RBF_F * (p00 * p00 + p01 * p01);
        b.y = -RBF_F * (p10 * p10 + p11 * p11);
        b.z = w2[2 * q];           b.w = w2[2 * q + 1];
        c[2 * q]     = a;
        c[2 * q + 1] = b;
    }
}

__global__ __launch_bounds__(THREADS) void
rbf_kernel(const float* __restrict__ X,
           const float4* __restrict__ c,
           float* __restrict__ out) {
    const int t    = threadIdx.x;
    const int lane = t & 63;
    const int w    = __builtin_amdgcn_readfirstlane(t >> 6);  // 0..3
    const int xg   = w >> 1;
    const int ph   = w & 1;

    // MX wave-uniform x-values, hoisted as persistent splat pairs
    const int xb = blockIdx.x * XPB + xg * MX;
    const float2* Xp = (const float2*)X;
    v2f xs0[MX], xs1[MX];
#pragma unroll
    for (int i = 0; i < MX; ++i) {
        float2 xv = Xp[xb + i];
        xs0[i] = (v2f){xv.x, xv.x};
        xs1[i] = (v2f){xv.y, xv.y};
    }

    v2f num2[MX], den2[MX];
#pragma unroll
    for (int i = 0; i < MX; ++i) {
        num2[i] = (v2f){0.f, 0.f};
        den2[i] = (v2f){0.f, 0.f};
    }

    // this wave's pattern-pair stream (L2-resident, coalesced 2 KB/wave/iter)
    const float4* __restrict__ C4 = c + (size_t)ph * (2 * PAIRS_PER_PH);

    float4 a = C4[2 * lane];
    float4 b = C4[2 * lane + 1];

    for (int j = 0; j < ITERS; ++j) {
        // branch-free wrapped prefetch of next iteration's pair
        const int qn = (((j + 1) & (ITERS - 1)) << 6) + lane;
        float4 an = C4[2 * qn];
        float4 bn = C4[2 * qn + 1];

#pragma unroll
        for (int i = 0; i < MX; ++i) {
            // arg for patterns (2q, 2q+1) at x_i — all operands are direct
            // register pairs: v_pk_fma_f32 ×2, v_exp_f32 ×2, v_pk_add, v_pk_fma
            v2f tt = __builtin_elementwise_fma((v2f){a.x, a.y}, xs0[i],
                                               (v2f){b.x, b.y});
            tt = __builtin_elementwise_fma((v2f){a.z, a.w}, xs1[i], tt);
            v2f k = (v2f){fast_exp2(tt.x), fast_exp2(tt.y)};
            den2[i] += k;
            num2[i] = __builtin_elementwise_fma(k, (v2f){b.z, b.w}, num2[i]);
        }
        a = an;
        b = bn;
    }

    // fold pattern-pair halves, then 6-step butterfly across the wave
    float num[MX], den[MX];
#pragma unroll
    for (int i = 0; i < MX; ++i) {
        num[i] = num2[i].x + num2[i].y;
        den[i] = den2[i].x + den2[i].y;
    }
#pragma unroll
    for (int m = 1; m < 64; m <<= 1) {
#pragma unroll
        for (int i = 0; i < MX; ++i) {
            num[i] += __shfl_xor(num[i], m, 64);
            den[i] += __shfl_xor(den[i], m, 64);
        }
    }

    __shared__ float red[XG][PH][MX][2];
    if (lane == 0) {
#pragma unroll
        for (int i = 0; i < MX; ++i) {
            red[xg][ph][i][0] = num[i];
            red[xg][ph][i][1] = den[i];
        }
    }
    __syncthreads();

    if (t < XPB) {
        int g = t / MX, xi = t % MX;
        float nn = red[g][0][xi][0] + red[g][1][xi][0];
        float dd = red[g][0][xi][1] + red[g][1][xi][1];
        out[blockIdx.x * XPB + t] = nn / dd;
    }
}

extern "C" void kernel_launch(void* const* d_in, const int* in_sizes, int n_in,
                              void* d_out, int out_size, void* d_ws, size_t ws_size,
                              hipStream_t stream) {
    const float* X   = (const float*)d_in[0];   // [32768, 2]
    const float* pat = (const float*)d_in[1];   // [8192, 2]
    const float* w2  = (const float*)d_in[2];   // [8192]
    float* out = (float*)d_out;                 // [32768]
    float4* c = (float4*)d_ws;                  // 8192 * 16 B = 128 KB

    prep_kernel<<<(P / 2 + 255) / 256, 256, 0, stream>>>(pat, w2, c);
    rbf_kernel<<<NBLK, THREADS, 0, stream>>>(X, c, out);
}

// Round 3
// 93.705 us; speedup vs baseline: 1.1887x; 1.0686x over previous
//
#include <hip/hip_runtime.h>

#define N 32768
#define P 8192
#define MX 8                          // x-values per wave (wave-uniform)
#define XG 4                          // x-groups per block
#define PH 2                          // pattern halves
#define THREADS (XG * PH * 64)        // 512
#define XPB (XG * MX)                 // 32 x per block
#define NBLK (N / XPB)                // 1024 (4 blocks/CU, 8 waves each)
#define PAIRS (P / 2)                 // 4096 pattern-pairs
#define PAIRS_PER_PH (PAIRS / PH)     // 2048
#define ITERS (PAIRS_PER_PH / 64)     // 32 (power of 2 — wrap prefetch)

// f = log2(e)/(2*sigma^2), sigma^2 = 1.44; per-x |x|^2 cancels in num/den.
#define RBF_F 0.50093577808645257f

typedef float v2f __attribute__((ext_vector_type(2)));

static __device__ __forceinline__ float fast_exp2(float x) {
#if __has_builtin(__builtin_amdgcn_exp2f)
    return __builtin_amdgcn_exp2f(x);
#else
    return exp2f(x);
#endif
}

// Pair-interleaved constants for pattern pair q = (2q, 2q+1):
//   c[2q]   = { c0(2q), c0(2q+1), c1(2q), c1(2q+1) }
//   c[2q+1] = { c2(2q), c2(2q+1), w(2q),  w(2q+1)  }
__global__ void prep_kernel(const float* __restrict__ pat,
                            const float* __restrict__ w2,
                            float4* __restrict__ c) {
    int q = blockIdx.x * blockDim.x + threadIdx.x;
    if (q < P / 2) {
        float p00 = pat[4 * q + 0], p01 = pat[4 * q + 1];
        float p10 = pat[4 * q + 2], p11 = pat[4 * q + 3];
        float4 a, b;
        a.x = 2.0f * RBF_F * p00;  a.y = 2.0f * RBF_F * p10;
        a.z = 2.0f * RBF_F * p01;  a.w = 2.0f * RBF_F * p11;
        b.x = -RBF_F * (p00 * p00 + p01 * p01);
        b.y = -RBF_F * (p10 * p10 + p11 * p11);
        b.z = w2[2 * q];           b.w = w2[2 * q + 1];
        c[2 * q]     = a;
        c[2 * q + 1] = b;
    }
}

// inner body: v_pk_fma ×2, v_exp ×2, v_pk_add, v_pk_fma per pattern-pair×x
#define BODY(aa, bb)                                                          \
    _Pragma("unroll")                                                         \
    for (int i = 0; i < MX; ++i) {                                            \
        v2f tt = __builtin_elementwise_fma((v2f){(aa).x, (aa).y}, xs0[i],     \
                                           (v2f){(bb).x, (bb).y});            \
        tt = __builtin_elementwise_fma((v2f){(aa).z, (aa).w}, xs1[i], tt);    \
        v2f k = (v2f){fast_exp2(tt.x), fast_exp2(tt.y)};                      \
        den2[i] += k;                                                         \
        num2[i] = __builtin_elementwise_fma(k, (v2f){(bb).z, (bb).w},         \
                                            num2[i]);                        \
    }

__global__ __launch_bounds__(THREADS, 4) void
rbf_kernel(const float* __restrict__ X,
           const float4* __restrict__ c,
           float* __restrict__ out) {
    const int t    = threadIdx.x;
    const int lane = t & 63;
    const int w    = __builtin_amdgcn_readfirstlane(t >> 6);  // 0..7
    const int xg   = w >> 1;
    const int ph   = w & 1;

    // MX wave-uniform x-values, hoisted as persistent splat pairs
    const int xb = blockIdx.x * XPB + xg * MX;
    const float2* Xp = (const float2*)X;
    v2f xs0[MX], xs1[MX];
#pragma unroll
    for (int i = 0; i < MX; ++i) {
        float2 xv = Xp[xb + i];
        xs0[i] = (v2f){xv.x, xv.x};
        xs1[i] = (v2f){xv.y, xv.y};
    }

    v2f num2[MX], den2[MX];
#pragma unroll
    for (int i = 0; i < MX; ++i) {
        num2[i] = (v2f){0.f, 0.f};
        den2[i] = (v2f){0.f, 0.f};
    }

    // this wave's pattern-pair stream (L2-resident, coalesced 2 KB/wave/iter)
    const float4* __restrict__ C4 = c + (size_t)ph * (2 * PAIRS_PER_PH);

    // per-block ring-phase desync: blocks start at different table offsets
    // (breaks the all-waves-on-one-hot-line convoy; sum order per block
    // changes only by rotation — fp-assoc noise ≪ tolerance)
    const int phase = blockIdx.x & (ITERS - 1);

    // double-buffered, prefetch depth 2, hand-unrolled (no runtime reg idx)
    const int s0 = 2 * (((phase & (ITERS - 1)) << 6) + lane);
    const int s1 = 2 * ((((phase + 1) & (ITERS - 1)) << 6) + lane);
    float4 A0 = C4[s0], B0 = C4[s0 + 1];
    float4 A1 = C4[s1], B1 = C4[s1 + 1];

    for (int j = 0; j < ITERS; j += 2) {
        const int s2 = 2 * ((((phase + j + 2) & (ITERS - 1)) << 6) + lane);
        float4 an = C4[s2], bn = C4[s2 + 1];   // issued ~2 bodies before use
        BODY(A0, B0)
        const int s3 = 2 * ((((phase + j + 3) & (ITERS - 1)) << 6) + lane);
        float4 am = C4[s3], bm = C4[s3 + 1];
        BODY(A1, B1)
        A0 = an; B0 = bn;
        A1 = am; B1 = bm;
    }

    // fold pattern-pair halves, then 6-step butterfly across the wave
    float num[MX], den[MX];
#pragma unroll
    for (int i = 0; i < MX; ++i) {
        num[i] = num2[i].x + num2[i].y;
        den[i] = den2[i].x + den2[i].y;
    }
#pragma unroll
    for (int m = 1; m < 64; m <<= 1) {
#pragma unroll
        for (int i = 0; i < MX; ++i) {
            num[i] += __shfl_xor(num[i], m, 64);
            den[i] += __shfl_xor(den[i], m, 64);
        }
    }

    __shared__ float red[XG][PH][MX][2];
    if (lane == 0) {
#pragma unroll
        for (int i = 0; i < MX; ++i) {
            red[xg][ph][i][0] = num[i];
            red[xg][ph][i][1] = den[i];
        }
    }
    __syncthreads();

    if (t < XPB) {
        int g = t >> 3, xi = t & 7;   // t / MX, t % MX (MX=8)
        float nn = red[g][0][xi][0] + red[g][1][xi][0];
        float dd = red[g][0][xi][1] + red[g][1][xi][1];
        out[blockIdx.x * XPB + t] = nn / dd;
    }
}

extern "C" void kernel_launch(void* const* d_in, const int* in_sizes, int n_in,
                              void* d_out, int out_size, void* d_ws, size_t ws_size,
                              hipStream_t stream) {
    const float* X   = (const float*)d_in[0];   // [32768, 2]
    const float* pat = (const float*)d_in[1];   // [8192, 2]
    const float* w2  = (const float*)d_in[2];   // [8192]
    float* out = (float*)d_out;                 // [32768]
    float4* c = (float4*)d_ws;                  // 8192 * 16 B = 128 KB

    prep_kernel<<<(P / 2 + 255) / 256, 256, 0, stream>>>(pat, w2, c);
    rbf_kernel<<<NBLK, THREADS, 0, stream>>>(X, c, out);
}